// Round 1
// baseline (11397.556 us; speedup 1.0000x reference)
//
#include <hip/hip_runtime.h>
#include <hip/hip_bf16.h>

#define B_ 256
#define T_ 512
#define D_ 256
#define H_ 1024
#define C_ 10

typedef __attribute__((ext_vector_type(8))) short short8;
typedef __attribute__((ext_vector_type(4))) float floatx4;

static __device__ __forceinline__ unsigned short f2bf(float f) {
    __hip_bfloat16 b = __float2bfloat16(f);
    return *reinterpret_cast<unsigned short*>(&b);
}
static __device__ __forceinline__ float bf2f(unsigned short u) {
    unsigned int v = ((unsigned int)u) << 16;
    return __uint_as_float(v);
}

// ---------------------------------------------------------------------------
// Pack Wh gates into WhT[gate][j][k] = bf16(W_gate_h[k][j])  (transposed, bf16)
// grid: (32 j-tiles, 32 k-tiles, 4 gates), block 256
// ---------------------------------------------------------------------------
__global__ void lstm_pack_wht(const float* __restrict__ Wg,
                              const float* __restrict__ Wi,
                              const float* __restrict__ Wf,
                              const float* __restrict__ Wo,
                              unsigned short* __restrict__ WT) {
    __shared__ float tile[32][33];
    int g = blockIdx.z;
    const float* W = (g == 0) ? Wg : (g == 1) ? Wi : (g == 2) ? Wf : Wo;
    int j0 = blockIdx.x * 32;
    int k0 = blockIdx.y * 32;
    int tx = threadIdx.x & 31, ty = threadIdx.x >> 5;  // 32 x 8
    #pragma unroll
    for (int s = 0; s < 32; s += 8)
        tile[ty + s][tx] = W[(size_t)(k0 + ty + s) * H_ + j0 + tx];
    __syncthreads();
    unsigned short* out = WT + ((size_t)g << 20);  // g * 1024 * 1024
    #pragma unroll
    for (int s = 0; s < 32; s += 8) {
        int j = j0 + ty + s;
        out[(size_t)j * H_ + k0 + tx] = f2bf(tile[tx][ty + s]);
    }
}

// ---------------------------------------------------------------------------
// proj3[v][col] = sum_d emb[v][d] * Wx[d][col] + b[col], col in [0,4096)
// grid: (16, 3), block 256
// ---------------------------------------------------------------------------
__global__ void lstm_proj3(const float* __restrict__ emb,
                           const float* __restrict__ Wgx, const float* __restrict__ Wix,
                           const float* __restrict__ Wfx, const float* __restrict__ Wox,
                           const float* __restrict__ bg, const float* __restrict__ bi,
                           const float* __restrict__ bf_, const float* __restrict__ bo,
                           float* __restrict__ proj3) {
    int col = blockIdx.x * 256 + threadIdx.x;  // 0..4095
    int v = blockIdx.y;                        // 0..2
    int gate = col >> 10;
    int j = col & (H_ - 1);
    const float* Wx = (gate == 0) ? Wgx : (gate == 1) ? Wix : (gate == 2) ? Wfx : Wox;
    const float* bb = (gate == 0) ? bg : (gate == 1) ? bi : (gate == 2) ? bf_ : bo;
    float acc = bb[j];
    for (int d = 0; d < D_; ++d)
        acc += emb[v * D_ + d] * Wx[(size_t)d * H_ + j];
    proj3[(size_t)v * 4096 + col] = acc;
}

// ---------------------------------------------------------------------------
// One LSTM time step, fused GEMM + gates.
// grid 256 WGs (8 row-tiles x 32 col-tiles, XCD-swizzled), block 256 = 4 waves.
// Wave w computes the 32x32 tile of gate w: z_pre = h @ Wh_gate  (bf16 MFMA).
// Then all threads combine the 4 gates, update c (f32, in place) and write
// h_out (bf16, ping-pong buffer).
// ---------------------------------------------------------------------------
__launch_bounds__(256)
__global__ void lstm_step(const unsigned short* __restrict__ h_in,   // bf16 256x1024
                          const unsigned short* __restrict__ WhT,    // bf16 4x1024x1024 (j-major)
                          const float* __restrict__ proj3,           // 3x4096
                          const int* __restrict__ x,                 // 256x512
                          int t,
                          float* __restrict__ c,                     // f32 256x1024 (in place)
                          unsigned short* __restrict__ h_out) {      // bf16 256x1024
    int bid = blockIdx.x;
    // XCD-aware swizzle: XCD = bid&7 owns col_tiles 4*xcd .. 4*xcd+3 (1MB B slice -> L2 resident)
    int xcd = bid & 7;
    int idx = bid >> 3;
    int col_tile = xcd * 4 + (idx & 3);
    int row_tile = idx >> 2;  // 0..7
    int r0 = row_tile * 32;
    int j0 = col_tile * 32;

    int wave = threadIdx.x >> 6;  // = gate index
    int lane = threadIdx.x & 63;
    int lr = lane & 15;
    int lk = (lane >> 4) * 8;

    const unsigned short* Wg = WhT + ((size_t)wave << 20);

    floatx4 acc[2][2] = {};
    #pragma unroll 4
    for (int kk = 0; kk < H_; kk += 32) {
        short8 a0 = *(const short8*)(h_in + (size_t)(r0 + lr) * H_ + kk + lk);
        short8 a1 = *(const short8*)(h_in + (size_t)(r0 + 16 + lr) * H_ + kk + lk);
        short8 b0 = *(const short8*)(Wg + (size_t)(j0 + lr) * H_ + kk + lk);
        short8 b1 = *(const short8*)(Wg + (size_t)(j0 + 16 + lr) * H_ + kk + lk);
        acc[0][0] = __builtin_amdgcn_mfma_f32_16x16x32_bf16(a0, b0, acc[0][0], 0, 0, 0);
        acc[0][1] = __builtin_amdgcn_mfma_f32_16x16x32_bf16(a0, b1, acc[0][1], 0, 0, 0);
        acc[1][0] = __builtin_amdgcn_mfma_f32_16x16x32_bf16(a1, b0, acc[1][0], 0, 0, 0);
        acc[1][1] = __builtin_amdgcn_mfma_f32_16x16x32_bf16(a1, b1, acc[1][1], 0, 0, 0);
    }

    // Write z_pre tiles to LDS: zbuf[gate][row][col]
    __shared__ float zbuf[4][32][33];
    #pragma unroll
    for (int m = 0; m < 2; ++m)
        #pragma unroll
        for (int n = 0; n < 2; ++n)
            #pragma unroll
            for (int r = 0; r < 4; ++r) {
                int row = 16 * m + (lane >> 4) * 4 + r;
                int col = 16 * n + lr;
                zbuf[wave][row][col] = acc[m][n][r];
            }
    __syncthreads();

    // Gate combine: 1024 elements, 256 threads, 4 each
    int colc = threadIdx.x & 31;
    int rbase = threadIdx.x >> 5;  // 0..7
    #pragma unroll
    for (int s = 0; s < 4; ++s) {
        int r = rbase + 8 * s;
        int brow = r0 + r;
        int tok = x[(size_t)brow * T_ + t];
        const float* p3 = proj3 + (size_t)tok * 4096;
        int jj = j0 + colc;
        float zg = tanhf(zbuf[0][r][colc] + p3[jj]);
        float zi = tanhf(zbuf[1][r][colc] + p3[H_ + jj]);
        float zf = tanhf(zbuf[2][r][colc] + p3[2 * H_ + jj]);
        float zo = tanhf(zbuf[3][r][colc] + p3[3 * H_ + jj]);
        size_t cidx = (size_t)brow * H_ + jj;
        float cv = c[cidx];
        cv = zg * zi + cv * zf;
        c[cidx] = cv;
        h_out[cidx] = f2bf(tanhf(cv) * zo);
    }
}

// ---------------------------------------------------------------------------
// Final projection + log_softmax. One block (64 threads) per batch row.
// ---------------------------------------------------------------------------
__global__ void lstm_final(const unsigned short* __restrict__ h,  // bf16 256x1024
                           const float* __restrict__ Wp,          // 1024x10
                           const float* __restrict__ bp,          // 10
                           float* __restrict__ out) {             // 256x10
    int row = blockIdx.x;
    int lane = threadIdx.x;  // 0..63
    float acc[C_];
    #pragma unroll
    for (int cc = 0; cc < C_; ++cc) acc[cc] = 0.f;
    for (int k = lane; k < H_; k += 64) {
        float hv = bf2f(h[(size_t)row * H_ + k]);
        #pragma unroll
        for (int cc = 0; cc < C_; ++cc) acc[cc] += hv * Wp[(size_t)k * C_ + cc];
    }
    #pragma unroll
    for (int cc = 0; cc < C_; ++cc)
        #pragma unroll
        for (int off = 32; off > 0; off >>= 1)
            acc[cc] += __shfl_down(acc[cc], off);
    if (lane == 0) {
        float p[C_];
        float m = -1e30f;
        #pragma unroll
        for (int cc = 0; cc < C_; ++cc) {
            p[cc] = acc[cc] + bp[cc];
            m = fmaxf(m, p[cc]);
        }
        float se = 0.f;
        #pragma unroll
        for (int cc = 0; cc < C_; ++cc) se += expf(p[cc] - m);
        float lse = m + logf(se);
        #pragma unroll
        for (int cc = 0; cc < C_; ++cc) out[(size_t)row * C_ + cc] = p[cc] - lse;
    }
}

extern "C" void kernel_launch(void* const* d_in, const int* in_sizes, int n_in,
                              void* d_out, int out_size, void* d_ws, size_t ws_size,
                              hipStream_t stream) {
    const int* x = (const int*)d_in[0];
    const float* emb = (const float*)d_in[1];
    const float* W_gx = (const float*)d_in[2];
    const float* W_gh = (const float*)d_in[3];
    const float* b_g = (const float*)d_in[4];
    const float* W_ix = (const float*)d_in[5];
    const float* W_ih = (const float*)d_in[6];
    const float* b_i = (const float*)d_in[7];
    const float* W_fx = (const float*)d_in[8];
    const float* W_fh = (const float*)d_in[9];
    const float* b_f = (const float*)d_in[10];
    const float* W_ox = (const float*)d_in[11];
    const float* W_oh = (const float*)d_in[12];
    const float* b_o = (const float*)d_in[13];
    const float* W_ph = (const float*)d_in[14];
    const float* b_p = (const float*)d_in[15];
    float* out = (float*)d_out;

    // workspace layout
    char* ws = (char*)d_ws;
    unsigned short* WhT = (unsigned short*)ws;            // 4*1024*1024*2 = 8 MB
    size_t off = (size_t)4 * 1024 * 1024 * 2;
    float* proj3 = (float*)(ws + off); off += 3 * 4096 * 4;          // 48 KB
    float* c = (float*)(ws + off); off += (size_t)B_ * H_ * 4;       // 1 MB
    unsigned short* hbuf0 = (unsigned short*)(ws + off); off += (size_t)B_ * H_ * 2;  // 0.5 MB
    unsigned short* hbuf1 = (unsigned short*)(ws + off); off += (size_t)B_ * H_ * 2;  // 0.5 MB

    // 1. pack WhT (bf16, transposed)
    lstm_pack_wht<<<dim3(32, 32, 4), 256, 0, stream>>>(W_gh, W_ih, W_fh, W_oh, WhT);
    // 2. proj3 = emb @ Wx + b   (3 x 4096)
    lstm_proj3<<<dim3(16, 3), 256, 0, stream>>>(emb, W_gx, W_ix, W_fx, W_ox,
                                                b_g, b_i, b_f, b_o, proj3);
    // 3. zero-init c and h0
    hipMemsetAsync(c, 0, (size_t)B_ * H_ * 4, stream);
    hipMemsetAsync(hbuf0, 0, (size_t)B_ * H_ * 2, stream);

    // 4. recurrence
    unsigned short* hb[2] = {hbuf0, hbuf1};
    for (int t = 0; t < T_; ++t) {
        lstm_step<<<256, 256, 0, stream>>>(hb[t & 1], WhT, proj3, x, t, c, hb[(t + 1) & 1]);
    }

    // 5. final projection + log_softmax (final h is in hbuf0 since T_ is even)
    lstm_final<<<B_, 64, 0, stream>>>(hbuf0, W_ph, b_p, out);
}